// Round 13
// baseline (30.510 us; speedup 1.0000x reference)
//
#include <hip/hip_runtime.h>
#include <math.h>

#define SZ 28

__constant__ int c_fy[10] = {4,4,4,14,14,14,24,24,24,12};
__constant__ int c_fx[10] = {4,14,24,4,14,24,4,14,24,12};

typedef __attribute__((ext_vector_type(4)))  float    f32x4;
typedef __attribute__((ext_vector_type(16))) float    f32x16;
typedef __attribute__((ext_vector_type(8)))  _Float16 f16x8;

// ---------------------------------------------------------------------------
// Prep (R8 version, verified): 49 blocks, one per kstep s; each computes the
// 28-pt DFT table redundantly, threads 0..15 emit the 1 KB w2 slab.
// B-frag for mfma_f32_32x32x16_f16: lane l holds B[k=s*16+(l>>5)*8+j][col=l&31]
// w2[s*512 + ((b*32)+v)*8 + j], b=(k>>3)&1; cols v: 2p=Re(p), 2p+1=Im(p).
// ---------------------------------------------------------------------------
__global__ __launch_bounds__(784) void prep_weights(const float* __restrict__ phase,
                                                    _Float16* __restrict__ w2) {
    __shared__ float tr[SZ][SZ], ti[SZ][SZ];
    __shared__ float g1r[SZ], g1i[SZ];
    const int tid = threadIdx.x;                    // 0..783
    const int s = blockIdx.x;                       // kstep 0..48
    {
        const int t = tid / SZ, k = tid % SZ;
        const int m = (k <= SZ / 2) ? k : SZ - k;
        int num = (14 * k * t - m * m) % 392; if (num < 0) num += 392;
        float sn, cs;
        sincosf((float)num * (6.283185307179586f / 392.0f), &sn, &cs);
        tr[t][k] = cs; ti[t][k] = sn;
    }
    __syncthreads();
    if (tid < SZ) {
        float ar = 0.f, ai = 0.f;
        for (int k = 0; k < SZ; ++k) { ar += tr[tid][k]; ai += ti[tid][k]; }
        g1r[tid] = ar / 28.f; g1i[tid] = ai / 28.f;
    }
    __syncthreads();
    if (tid < 16) {
        const int k = s * 16 + tid;                 // pixel 0..783
        const int y = k / SZ, x = k % SZ;
        float Wv[20];
        float sp, cp; sincosf(phase[k], &sp, &cp);
        #pragma unroll
        for (int p = 0; p < 10; ++p) {
            const int dy = (c_fy[p] - y + SZ) % SZ;
            const int dx = (c_fx[p] - x + SZ) % SZ;
            const float Gr = g1r[dy] * g1r[dx] - g1i[dy] * g1i[dx];
            const float Gi = g1r[dy] * g1i[dx] + g1i[dy] * g1r[dx];
            Wv[p]      = cp * Gr - sp * Gi;          // Re
            Wv[10 + p] = cp * Gi + sp * Gr;          // Im
        }
        const int b = tid >> 3, j = tid & 7;
        #pragma unroll
        for (int v = 0; v < 32; ++v) {
            float val = 0.f;
            if (v < 20) val = (v & 1) ? Wv[10 + (v >> 1)] : Wv[v >> 1];
            w2[s * 512 + (b * 32 + v) * 8 + j] = (_Float16)val;
        }
    }
}

// ---------------------------------------------------------------------------
// Main MFMA GEMM — R12 core + 3-deep register A-prefetch (T14 at depth 3):
// block = 256 thr = 4 waves (kq kstep-quarter {2,2,2,1}), 32 rows, grid 1024.
// Loop iter c: [loadA(c+3) issues] -> compute(c) -> [writeA(c+1): its v regs
// were loaded at iter c-2, ~2 full iterations of latency cover] -> barrier.
// Prologue issues x loads for chunks 0..2 BEFORE the 53 KB B-fragment reg
// loads, so the block head overlaps x latency instead of adding to it.
// W: 14 B-frags in registers (kq==3 pads slot 1 with zero, static indexing).
// A: reg-staged f32->f16 (cvt_pkrtz) into fragment-order LDS (lane^s
// swizzle), double-buffered 2x7168. Epilogue: 4-way kq reduce + |.|^2.
// ---------------------------------------------------------------------------
__global__ __launch_bounds__(256) void focus_gemm(const float* __restrict__ x,
                                                  const _Float16* __restrict__ w2,
                                                  float* __restrict__ out) {
    __shared__ char smem[14336];                 // 2 x 7168 bufA; alias: red

    const int tid  = threadIdx.x;
    const int lane = tid & 63;
    const int kq = __builtin_amdgcn_readfirstlane(tid >> 6);  // 0..3
    const int row0 = blockIdx.x * 32;

    // ---- A staging helpers: 896 f4 per chunk (32 rows x 28), 3.5/thread ----
    auto loadA = [&](f32x4* v, int c) {
        const f32x4* x4 = (const f32x4*)x;
        #pragma unroll
        for (int i = 0; i < 4; ++i) {
            const int g = i * 256 + tid;
            if (g < 896) {
                const int r = g / 28, c4 = g % 28;
                v[i] = x4[(size_t)(row0 + r) * 196 + c * 28 + c4];
            }
        }
    };
    auto writeA = [&](const f32x4* v, int c) {
        char* buf = smem + (c & 1) * 7168;
        #pragma unroll
        for (int i = 0; i < 4; ++i) {
            const int g = i * 256 + tid;
            if (g < 896) {
                const int r = g / 28, c4 = g % 28;
                const int s = c4 >> 2, b = (c4 >> 1) & 1;
                const int ln = ((r & 31) + (b << 5)) ^ s;
                auto lo = __builtin_amdgcn_cvt_pkrtz(v[i].x, v[i].y);
                auto hi = __builtin_amdgcn_cvt_pkrtz(v[i].z, v[i].w);
                uint2 d;
                d.x = __builtin_bit_cast(unsigned int, lo);
                d.y = __builtin_bit_cast(unsigned int, hi);
                *(uint2*)(buf + (s * 64 + ln) * 16 + (c4 & 1) * 8) = d;
            }
        }
    };

    // ---- Prologue: x prefetch for chunks 0..2 FIRST (latency head-start) ----
    f32x4 vreg[3][4];                            // statically indexed via unroll
    loadA(vreg[0], 0);
    loadA(vreg[1], 1);
    loadA(vreg[2], 2);

    // ---- B fragments to registers (L2-hot; overlaps x latency above) ----
    f16x8 bfr[14];
    #pragma unroll
    for (int c = 0; c < 7; ++c) {
        bfr[2 * c] = *(const f16x8*)(w2 + (size_t)(c * 7 + 2 * kq) * 512 + lane * 8);
        if (kq < 3) {
            bfr[2 * c + 1] =
                *(const f16x8*)(w2 + (size_t)(c * 7 + 2 * kq + 1) * 512 + lane * 8);
        } else {
            f16x8 z;
            #pragma unroll
            for (int i = 0; i < 8; ++i) z[i] = (_Float16)0.f;
            bfr[2 * c + 1] = z;                  // pad: B=0 -> MFMA no-op
        }
    }

    f32x16 acc;
    #pragma unroll
    for (int i = 0; i < 16; ++i) acc[i] = 0.f;

    writeA(vreg[0], 0);                          // buf0 <- chunk 0
    #pragma unroll
    for (int c = 0; c < 7; ++c) {
        __syncthreads();                         // publishes chunk c bufA
        if (c + 3 < 7) loadA(vreg[(c + 3) % 3], c + 3);   // 3-deep prefetch
        {
            char* bA = smem + (c & 1) * 7168;
            #pragma unroll
            for (int sl = 0; sl < 2; ++sl) {
                const int s = (kq == 3) ? 6 : 2 * kq + sl;   // A kstep in chunk
                f16x8 a = *(const f16x8*)(bA + (s * 64 + (lane ^ s)) * 16);
                acc = __builtin_amdgcn_mfma_f32_32x32x16_f16(a, bfr[2 * c + sl],
                                                             acc, 0, 0, 0);
            }
        }
        if (c + 1 < 7) writeA(vreg[(c + 1) % 3], c + 1);  // v loaded 2 iters ago
    }

    // ---- Epilogue: 4-way kq reduction + |.|^2 (red aliases bufA) ----
    __syncthreads();
    float* red = (float*)smem;                   // [3][64][17] = 13056 B
    if (kq > 0) {
        #pragma unroll
        for (int i = 0; i < 16; ++i)
            red[((kq - 1) * 64 + lane) * 17 + i] = acc[i];
    }
    __syncthreads();
    if (kq == 0) {
        const int col = lane & 31;
        #pragma unroll
        for (int i = 0; i < 16; ++i) {
            const float sum = acc[i]
                + red[(0 * 64 + lane) * 17 + i]
                + red[(1 * 64 + lane) * 17 + i]
                + red[(2 * 64 + lane) * 17 + i];
            const float sq = sum * sum;
            const float tot = sq + __shfl_xor(sq, 1, 64);
            if ((col & 1) == 0 && col < 20) {
                const int r = (i & 3) + 8 * (i >> 2) + 4 * (lane >> 5);
                out[(size_t)(row0 + r) * 10 + (col >> 1)] = tot;
            }
        }
    }
}

extern "C" void kernel_launch(void* const* d_in, const int* in_sizes, int n_in,
                              void* d_out, int out_size, void* d_ws, size_t ws_size,
                              hipStream_t stream) {
    const float* x     = (const float*)d_in[0];   // [32768,1,28,28] f32
    const float* phase = (const float*)d_in[1];   // [28,28] f32
    float* out = (float*)d_out;                   // [32768,10] f32
    _Float16* w2 = (_Float16*)d_ws;               // 49*512 f16 = 50 KB

    hipLaunchKernelGGL(prep_weights, dim3(49), dim3(SZ * SZ), 0, stream, phase, w2);

    const int B = in_sizes[0] / (SZ * SZ);        // 32768
    hipLaunchKernelGGL(focus_gemm, dim3(B / 32), dim3(256), 0, stream, x, w2, out);
}

// Round 14
// 26.914 us; speedup vs baseline: 1.1336x; 1.1336x over previous
//
#include <hip/hip_runtime.h>
#include <math.h>

#define SZ 28

__constant__ int c_fy[10] = {4,4,4,14,14,14,24,24,24,12};
__constant__ int c_fx[10] = {4,14,24,4,14,24,4,14,24,12};

typedef __attribute__((ext_vector_type(4)))  float    f32x4;
typedef __attribute__((ext_vector_type(16))) float    f32x16;
typedef __attribute__((ext_vector_type(8)))  _Float16 f16x8;

// ---------------------------------------------------------------------------
// Prep (R8 version, verified): 49 blocks, one per kstep s; each computes the
// 28-pt DFT table redundantly, threads 0..15 emit the 1 KB w2 slab.
// B-frag for mfma_f32_32x32x16_f16: lane l holds B[k=s*16+(l>>5)*8+j][col=l&31]
// w2[s*512 + ((b*32)+v)*8 + j], b=(k>>3)&1; cols v: 2p=Re(p), 2p+1=Im(p).
// ---------------------------------------------------------------------------
__global__ __launch_bounds__(784) void prep_weights(const float* __restrict__ phase,
                                                    _Float16* __restrict__ w2) {
    __shared__ float tr[SZ][SZ], ti[SZ][SZ];
    __shared__ float g1r[SZ], g1i[SZ];
    const int tid = threadIdx.x;                    // 0..783
    const int s = blockIdx.x;                       // kstep 0..48
    {
        const int t = tid / SZ, k = tid % SZ;
        const int m = (k <= SZ / 2) ? k : SZ - k;
        int num = (14 * k * t - m * m) % 392; if (num < 0) num += 392;
        float sn, cs;
        sincosf((float)num * (6.283185307179586f / 392.0f), &sn, &cs);
        tr[t][k] = cs; ti[t][k] = sn;
    }
    __syncthreads();
    if (tid < SZ) {
        float ar = 0.f, ai = 0.f;
        for (int k = 0; k < SZ; ++k) { ar += tr[tid][k]; ai += ti[tid][k]; }
        g1r[tid] = ar / 28.f; g1i[tid] = ai / 28.f;
    }
    __syncthreads();
    if (tid < 16) {
        const int k = s * 16 + tid;                 // pixel 0..783
        const int y = k / SZ, x = k % SZ;
        float Wv[20];
        float sp, cp; sincosf(phase[k], &sp, &cp);
        #pragma unroll
        for (int p = 0; p < 10; ++p) {
            const int dy = (c_fy[p] - y + SZ) % SZ;
            const int dx = (c_fx[p] - x + SZ) % SZ;
            const float Gr = g1r[dy] * g1r[dx] - g1i[dy] * g1i[dx];
            const float Gi = g1r[dy] * g1i[dx] + g1i[dy] * g1r[dx];
            Wv[p]      = cp * Gr - sp * Gi;          // Re
            Wv[10 + p] = cp * Gi + sp * Gr;          // Im
        }
        const int b = tid >> 3, j = tid & 7;
        #pragma unroll
        for (int v = 0; v < 32; ++v) {
            float val = 0.f;
            if (v < 20) val = (v & 1) ? Wv[10 + (v >> 1)] : Wv[v >> 1];
            w2[s * 512 + (b * 32 + v) * 8 + j] = (_Float16)val;
        }
    }
}

// ---------------------------------------------------------------------------
// Main MFMA GEMM — R9 core (best measured) + 2 read-path levers:
//  * non-temporal x loads (stream-once data, skip cache allocation)
//  * XCD-bijective block swizzle (grid 512 = 8*64 exact; contiguous
//    12.8 MB row-stripe per XCD for DRAM page/channel locality)
// block = 512 thr = 8 waves = (m mtile) x (kq kstep quarter {2,2,2,1}).
// x reg-staged f32->f16 (cvt_pkrtz) into fragment-order LDS (lane^s swizzle),
// double-buffered, 1 chunk ahead. W via global_load_lds (1KB/wave).
// LDS: bufA 2x14336 + bufB 2x7168 = 43008 B.
// ---------------------------------------------------------------------------
__device__ static inline void gload_lds16(const void* src, char* lds_dst) {
    __builtin_amdgcn_global_load_lds(
        (const __attribute__((address_space(1))) void*)src,
        (__attribute__((address_space(3))) void*)lds_dst, 16, 0, 0);
}

__global__ __launch_bounds__(512) void focus_gemm(const float* __restrict__ x,
                                                  const _Float16* __restrict__ w2,
                                                  float* __restrict__ out) {
    __shared__ char smem[43008];
    const int tid  = threadIdx.x;
    const int lane = tid & 63;
    const int w = __builtin_amdgcn_readfirstlane(tid >> 6);  // 0..7
    const int m = w >> 2;                                    // mtile
    const int kq = w & 3;                                    // kstep quarter
    // XCD-bijective swizzle: 512 blocks, 8 XCDs, 64 blocks/XCD chunk
    const int bid = blockIdx.x;
    const int row0 = ((bid & 7) * 64 + (bid >> 3)) * 64;

    f32x16 acc;
    #pragma unroll
    for (int i = 0; i < 16; ++i) acc[i] = 0.f;

    char* const bA0 = smem;                 // 2 x 14336
    char* const bB0 = smem + 28672;         // 2 x 7168

    auto stageB = [&](int c) {
        if (w < 7)
            gload_lds16(w2 + (c * 7 + w) * 512 + lane * 8,
                        bB0 + (c & 1) * 7168 + w * 1024);
    };
    auto loadA = [&](f32x4* v, int c) {
        const f32x4* x4 = (const f32x4*)x;
        #pragma unroll
        for (int i = 0; i < 4; ++i) {
            const int g = i * 512 + tid;
            if (g < 1792) {
                const int r = g / 28, c4 = g % 28;
                v[i] = __builtin_nontemporal_load(
                    x4 + (size_t)(row0 + r) * 196 + c * 28 + c4);
            }
        }
    };
    auto writeA = [&](const f32x4* v, int c) {
        char* buf = bA0 + (c & 1) * 14336;
        #pragma unroll
        for (int i = 0; i < 4; ++i) {
            const int g = i * 512 + tid;
            if (g < 1792) {
                const int r = g / 28, c4 = g % 28;
                const int s = c4 >> 2, b = (c4 >> 1) & 1;
                const int mt = r >> 5;
                const int ln = ((r & 31) + (b << 5)) ^ s;
                auto lo = __builtin_amdgcn_cvt_pkrtz(v[i].x, v[i].y);
                auto hi = __builtin_amdgcn_cvt_pkrtz(v[i].z, v[i].w);
                uint2 d;
                d.x = __builtin_bit_cast(unsigned int, lo);
                d.y = __builtin_bit_cast(unsigned int, hi);
                *(uint2*)(buf + ((s * 2 + mt) * 64 + ln) * 16 + (c4 & 1) * 8) = d;
            }
        }
    };
    auto compute = [&](int c) {
        char* bA = bA0 + (c & 1) * 14336;
        char* bB = bB0 + (c & 1) * 7168;
        const int sbeg = 2 * kq, send = (kq == 3) ? 7 : 2 * kq + 2;
        for (int s = sbeg; s < send; ++s) {
            f16x8 a = *(const f16x8*)(bA + ((s * 2 + m) * 64 + (lane ^ s)) * 16);
            f16x8 b = *(const f16x8*)(bB + s * 1024 + lane * 16);
            acc = __builtin_amdgcn_mfma_f32_32x32x16_f16(a, b, acc, 0, 0, 0);
        }
    };

    f32x4 v[4];
    stageB(0); loadA(v, 0); writeA(v, 0);
    for (int c = 0; c < 7; ++c) {
        __syncthreads();                         // publishes chunk c buffers
        if (c < 6) { stageB(c + 1); loadA(v, c + 1); }
        compute(c);
        if (c < 6) writeA(v, c + 1);
    }

    // ---- 4-way K reduction per mtile + |.|^2 epilogue ----
    __syncthreads();
    float* red = (float*)smem;                   // [2][3][64][17] = 25.5 KB
    if (kq > 0) {
        #pragma unroll
        for (int i = 0; i < 16; ++i)
            red[((m * 3 + (kq - 1)) * 64 + lane) * 17 + i] = acc[i];
    }
    __syncthreads();
    if (kq == 0) {
        const int col = lane & 31;
        #pragma unroll
        for (int i = 0; i < 16; ++i) {
            const float sum = acc[i]
                + red[((m * 3 + 0) * 64 + lane) * 17 + i]
                + red[((m * 3 + 1) * 64 + lane) * 17 + i]
                + red[((m * 3 + 2) * 64 + lane) * 17 + i];
            const float sq = sum * sum;
            const float tot = sq + __shfl_xor(sq, 1, 64);
            if ((col & 1) == 0 && col < 20) {
                const int r = (i & 3) + 8 * (i >> 2) + 4 * (lane >> 5);
                out[(size_t)(row0 + m * 32 + r) * 10 + (col >> 1)] = tot;
            }
        }
    }
}

extern "C" void kernel_launch(void* const* d_in, const int* in_sizes, int n_in,
                              void* d_out, int out_size, void* d_ws, size_t ws_size,
                              hipStream_t stream) {
    const float* x     = (const float*)d_in[0];   // [32768,1,28,28] f32
    const float* phase = (const float*)d_in[1];   // [28,28] f32
    float* out = (float*)d_out;                   // [32768,10] f32
    _Float16* w2 = (_Float16*)d_ws;               // 49*512 f16 = 50 KB

    hipLaunchKernelGGL(prep_weights, dim3(49), dim3(SZ * SZ), 0, stream, phase, w2);

    const int B = in_sizes[0] / (SZ * SZ);        // 32768
    hipLaunchKernelGGL(focus_gemm, dim3(B / 64), dim3(512), 0, stream, x, w2, out);
}